// Round 1
// baseline (18101.355 us; speedup 1.0000x reference)
//
#include <hip/hip_runtime.h>

#define NN 100000
#define EE 1600000
#define IN_DIM 128
#define HID 64
#define NH 4
#define DH 16
#define NL 3
#define OUT_DIM 64
#define SLOPE 0.2f
#define LN_EPS 1e-5f

__device__ __forceinline__ unsigned fenc(float f) {
    unsigned u = __float_as_uint(f);
    return (u & 0x80000000u) ? ~u : (u | 0x80000000u);
}
__device__ __forceinline__ float fdec(unsigned o) {
    unsigned u = (o & 0x80000000u) ? (o & 0x7FFFFFFFu) : ~o;
    return __uint_as_float(u);
}
__device__ __forceinline__ float lrelu(float x) {
    return x > 0.f ? x : SLOPE * x;
}

// h0 = X @ W_in + b_in   (N x 128) @ (128 x 64)
__global__ void k_in_gemm(const float* __restrict__ X, const float* __restrict__ W,
                          const float* __restrict__ b, float* __restrict__ h) {
    __shared__ float Ws[IN_DIM * HID];   // 32 KB
    for (int i = threadIdx.x; i < IN_DIM * HID; i += blockDim.x) Ws[i] = W[i];
    __syncthreads();
    const int j  = threadIdx.x & 63;   // output col (lane)
    const int vi = threadIdx.x >> 6;   // wave id in block (0..3)
    const float bj = b[j];
    for (int v0 = blockIdx.x * 4; v0 < NN; v0 += gridDim.x * 4) {
        const int v = v0 + vi;
        if (v >= NN) continue;
        const float* xr = X + (size_t)v * IN_DIM;
        float acc = bj;
#pragma unroll 8
        for (int k = 0; k < IN_DIM; ++k) acc += xr[k] * Ws[k * HID + j];
        h[(size_t)v * HID + j] = acc;
    }
}

// z = h @ W (64x64), plus el[v,h] = sum_d z*al, er[v,h] = sum_d z*ar
__global__ void k_zgemm(const float* __restrict__ h, const float* __restrict__ W,
                        const float* __restrict__ al, const float* __restrict__ ar,
                        float* __restrict__ z, float* __restrict__ el, float* __restrict__ er) {
    __shared__ float Ws[HID * HID];      // 16 KB
    for (int i = threadIdx.x; i < HID * HID; i += blockDim.x) Ws[i] = W[i];
    __syncthreads();
    const int j  = threadIdx.x & 63;
    const int vi = threadIdx.x >> 6;
    const int head = j >> 4;
    const float alj = al[j];   // a_l[h][d], flat index == j
    const float arj = ar[j];
    for (int v0 = blockIdx.x * 4; v0 < NN; v0 += gridDim.x * 4) {
        const int v = v0 + vi;
        if (v >= NN) continue;
        const float* hr = h + (size_t)v * HID;
        float acc = 0.f;
#pragma unroll 8
        for (int k = 0; k < HID; ++k) acc += hr[k] * Ws[k * HID + j];
        z[(size_t)v * HID + j] = acc;
        float pl = acc * alj, pr = acc * arj;
#pragma unroll
        for (int m = 8; m >= 1; m >>= 1) {
            pl += __shfl_xor(pl, m, 64);
            pr += __shfl_xor(pr, m, 64);
        }
        if ((j & 15) == 0) {
            el[v * NH + head] = pl;
            er[v * NH + head] = pr;
        }
    }
}

// acc = h + b_gat (residual folded in), zero m_enc/den
__global__ void k_init(const float* __restrict__ h, const float* __restrict__ b,
                       float* __restrict__ acc, unsigned* __restrict__ menc,
                       float* __restrict__ den) {
    const int i = blockIdx.x * blockDim.x + threadIdx.x;
    if (i < NN * HID) acc[i] = h[i] + b[i & 63];
    if (i < NN * NH) { menc[i] = 0u; den[i] = 0.f; }
}

__global__ void k_edge_max(const int* __restrict__ src, const int* __restrict__ dst,
                           const float* __restrict__ el, const float* __restrict__ er,
                           unsigned* __restrict__ menc) {
    const int e = blockIdx.x * blockDim.x + threadIdx.x;
    if (e >= EE) return;
    const int s = src[e], d = dst[e];
    const float4 l4 = *(const float4*)(el + (size_t)s * NH);
    const float4 r4 = *(const float4*)(er + (size_t)d * NH);
    float ev[4] = {l4.x + r4.x, l4.y + r4.y, l4.z + r4.z, l4.w + r4.w};
#pragma unroll
    for (int hh = 0; hh < NH; ++hh) {
        atomicMax(&menc[d * NH + hh], fenc(lrelu(ev[hh])));
    }
}

__global__ void k_edge_den(const int* __restrict__ src, const int* __restrict__ dst,
                           const float* __restrict__ el, const float* __restrict__ er,
                           const unsigned* __restrict__ menc, float* __restrict__ den) {
    const int e = blockIdx.x * blockDim.x + threadIdx.x;
    if (e >= EE) return;
    const int s = src[e], d = dst[e];
    const float4 l4 = *(const float4*)(el + (size_t)s * NH);
    const float4 r4 = *(const float4*)(er + (size_t)d * NH);
    float ev[4] = {l4.x + r4.x, l4.y + r4.y, l4.z + r4.z, l4.w + r4.w};
#pragma unroll
    for (int hh = 0; hh < NH; ++hh) {
        const float x = lrelu(ev[hh]);
        const float m = fdec(menc[d * NH + hh]);
        atomicAdd(&den[d * NH + hh], __expf(x - m));
    }
}

__global__ void k_edge_agg(const int* __restrict__ src, const int* __restrict__ dst,
                           const float* __restrict__ el, const float* __restrict__ er,
                           const unsigned* __restrict__ menc, const float* __restrict__ den,
                           const float* __restrict__ z, float* __restrict__ acc) {
    const int e = blockIdx.x * blockDim.x + threadIdx.x;
    if (e >= EE) return;
    const int s = src[e], d = dst[e];
    const float4 l4 = *(const float4*)(el + (size_t)s * NH);
    const float4 r4 = *(const float4*)(er + (size_t)d * NH);
    float ev[4] = {l4.x + r4.x, l4.y + r4.y, l4.z + r4.z, l4.w + r4.w};
    float alpha[4];
#pragma unroll
    for (int hh = 0; hh < NH; ++hh) {
        const float x = lrelu(ev[hh]);
        const float m = fdec(menc[d * NH + hh]);
        alpha[hh] = __expf(x - m) / den[d * NH + hh];
    }
    const float4* zr = (const float4*)(z + (size_t)s * HID);
    float* ar_ = acc + (size_t)d * HID;
#pragma unroll
    for (int k = 0; k < 16; ++k) {
        const float4 zv = zr[k];
        const float a = alpha[k >> 2];
        atomicAdd(ar_ + 4 * k + 0, zv.x * a);
        atomicAdd(ar_ + 4 * k + 1, zv.y * a);
        atomicAdd(ar_ + 4 * k + 2, zv.z * a);
        atomicAdd(ar_ + 4 * k + 3, zv.w * a);
    }
}

// LayerNorm + out = hn @ W_out + b_out, one wave per node
__global__ void k_ln_out(const float* __restrict__ h, const float* __restrict__ g,
                         const float* __restrict__ be, const float* __restrict__ Wo,
                         const float* __restrict__ bo, float* __restrict__ out) {
    __shared__ float Ws[HID * OUT_DIM];  // 16 KB
    for (int i = threadIdx.x; i < HID * OUT_DIM; i += blockDim.x) Ws[i] = Wo[i];
    __syncthreads();
    const int j  = threadIdx.x & 63;
    const int vi = threadIdx.x >> 6;
    const float gj = g[j], bej = be[j], boj = bo[j];
    for (int v0 = blockIdx.x * 4; v0 < NN; v0 += gridDim.x * 4) {
        const int v = v0 + vi;
        if (v >= NN) continue;
        const float x = h[(size_t)v * HID + j];
        float s = x;
#pragma unroll
        for (int m = 32; m >= 1; m >>= 1) s += __shfl_xor(s, m, 64);
        const float mu = s * (1.f / 64.f);
        const float dx = x - mu;
        float vs = dx * dx;
#pragma unroll
        for (int m = 32; m >= 1; m >>= 1) vs += __shfl_xor(vs, m, 64);
        const float hn = dx * rsqrtf(vs * (1.f / 64.f) + LN_EPS) * gj + bej;
        float acc = boj;
#pragma unroll
        for (int k = 0; k < HID; ++k) {
            const float hk = __shfl(hn, k, 64);
            acc += hk * Ws[k * OUT_DIM + j];
        }
        out[(size_t)v * OUT_DIM + j] = acc;
    }
}

extern "C" void kernel_launch(void* const* d_in, const int* in_sizes, int n_in,
                              void* d_out, int out_size, void* d_ws, size_t ws_size,
                              hipStream_t stream) {
    const float* X     = (const float*)d_in[0];
    const int*   src   = (const int*)d_in[1];
    const int*   dst   = (const int*)d_in[2];
    const float* W_in  = (const float*)d_in[3];
    const float* b_in  = (const float*)d_in[4];
    // d_in[5..8]: rewiring MLP params — output is dead, skipped entirely
    const float* W_gat = (const float*)d_in[9];   // (L,64,64)
    const float* a_l   = (const float*)d_in[10];  // (L,4,16)
    const float* a_r   = (const float*)d_in[11];
    const float* b_gat = (const float*)d_in[12];  // (L,64)
    const float* ln_g  = (const float*)d_in[13];
    const float* ln_b  = (const float*)d_in[14];
    const float* W_out = (const float*)d_in[15];
    const float* b_out = (const float*)d_in[16];
    float* out = (float*)d_out;

    float* ws = (float*)d_ws;
    float* hA = ws;                       // N*64
    float* hB = hA + (size_t)NN * HID;    // N*64
    float* z  = hB + (size_t)NN * HID;    // N*64
    float* el = z  + (size_t)NN * HID;    // N*4
    float* er = el + (size_t)NN * NH;     // N*4
    unsigned* menc = (unsigned*)(er + (size_t)NN * NH);  // N*4
    float* den = (float*)(menc + (size_t)NN * NH);       // N*4

    k_in_gemm<<<1024, 256, 0, stream>>>(X, W_in, b_in, hA);

    float* hin = hA;
    float* hout = hB;
    const int eg = (EE + 255) / 256;
    const int ig = (NN * HID + 255) / 256;
    for (int l = 0; l < NL; ++l) {
        k_zgemm<<<1024, 256, 0, stream>>>(hin, W_gat + (size_t)l * HID * HID,
                                          a_l + (size_t)l * HID, a_r + (size_t)l * HID,
                                          z, el, er);
        k_init<<<ig, 256, 0, stream>>>(hin, b_gat + (size_t)l * HID, hout, menc, den);
        k_edge_max<<<eg, 256, 0, stream>>>(src, dst, el, er, menc);
        k_edge_den<<<eg, 256, 0, stream>>>(src, dst, el, er, menc, den);
        k_edge_agg<<<eg, 256, 0, stream>>>(src, dst, el, er, menc, den, z, hout);
        float* t = hin; hin = hout; hout = t;
    }

    k_ln_out<<<1024, 256, 0, stream>>>(hin, ln_g, ln_b, W_out, b_out, out);
}

// Round 2
// 1316.769 us; speedup vs baseline: 13.7468x; 13.7468x over previous
//
#include <hip/hip_runtime.h>

#define NN 100000
#define EE 1600000
#define IN_DIM 128
#define HID 64
#define NH 4
#define DH 16
#define NL 3
#define OUT_DIM 64
#define SLOPE 0.2f
#define LN_EPS 1e-5f

#define SCAN_CHUNK 1024
#define NBLK ((NN + SCAN_CHUNK - 1) / SCAN_CHUNK)   // 98

__device__ __forceinline__ float lrelu(float x) {
    return x > 0.f ? x : SLOPE * x;
}

// h0 = X @ W_in + b_in   (N x 128) @ (128 x 64)
__global__ void k_in_gemm(const float* __restrict__ X, const float* __restrict__ W,
                          const float* __restrict__ b, float* __restrict__ h) {
    __shared__ float Ws[IN_DIM * HID];   // 32 KB
    for (int i = threadIdx.x; i < IN_DIM * HID; i += blockDim.x) Ws[i] = W[i];
    __syncthreads();
    const int j  = threadIdx.x & 63;
    const int vi = threadIdx.x >> 6;
    const float bj = b[j];
    for (int v0 = blockIdx.x * 4; v0 < NN; v0 += gridDim.x * 4) {
        const int v = v0 + vi;
        if (v >= NN) continue;
        const float* xr = X + (size_t)v * IN_DIM;
        float acc = bj;
#pragma unroll 8
        for (int k = 0; k < IN_DIM; ++k) acc += xr[k] * Ws[k * HID + j];
        h[(size_t)v * HID + j] = acc;
    }
}

// z = h @ W (64x64), plus el[v,h] = sum_d z*al, er[v,h] = sum_d z*ar
__global__ void k_zgemm(const float* __restrict__ h, const float* __restrict__ W,
                        const float* __restrict__ al, const float* __restrict__ ar,
                        float* __restrict__ z, float* __restrict__ el, float* __restrict__ er) {
    __shared__ float Ws[HID * HID];      // 16 KB
    for (int i = threadIdx.x; i < HID * HID; i += blockDim.x) Ws[i] = W[i];
    __syncthreads();
    const int j  = threadIdx.x & 63;
    const int vi = threadIdx.x >> 6;
    const int head = j >> 4;
    const float alj = al[j];
    const float arj = ar[j];
    for (int v0 = blockIdx.x * 4; v0 < NN; v0 += gridDim.x * 4) {
        const int v = v0 + vi;
        if (v >= NN) continue;
        const float* hr = h + (size_t)v * HID;
        float acc = 0.f;
#pragma unroll 8
        for (int k = 0; k < HID; ++k) acc += hr[k] * Ws[k * HID + j];
        z[(size_t)v * HID + j] = acc;
        float pl = acc * alj, pr = acc * arj;
#pragma unroll
        for (int m = 8; m >= 1; m >>= 1) {
            pl += __shfl_xor(pl, m, 64);
            pr += __shfl_xor(pr, m, 64);
        }
        if ((j & 15) == 0) {
            el[v * NH + head] = pl;
            er[v * NH + head] = pr;
        }
    }
}

// ---------------- CSR build (once per launch) ----------------

__global__ void k_zero_deg(int* __restrict__ deg) {
    const int i = blockIdx.x * blockDim.x + threadIdx.x;
    if (i < NN) deg[i] = 0;
}

__global__ void k_hist(const int* __restrict__ dst, int* __restrict__ deg) {
    const int e = blockIdx.x * blockDim.x + threadIdx.x;
    if (e < EE) atomicAdd(&deg[dst[e]], 1);
}

// per-1024-chunk sums
__global__ void k_blocksum(const int* __restrict__ deg, int* __restrict__ bsum) {
    const int b = blockIdx.x, t = threadIdx.x;
    const int i0 = b * SCAN_CHUNK + t * 4;
    int s = 0;
#pragma unroll
    for (int k = 0; k < 4; ++k) { const int i = i0 + k; if (i < NN) s += deg[i]; }
#pragma unroll
    for (int m = 32; m >= 1; m >>= 1) s += __shfl_xor(s, m, 64);
    __shared__ int wsum[4];
    if ((t & 63) == 0) wsum[t >> 6] = s;
    __syncthreads();
    if (t == 0) bsum[b] = wsum[0] + wsum[1] + wsum[2] + wsum[3];
}

// exclusive scan of the 98 block sums (single block, 128 threads)
__global__ void k_scanb(int* __restrict__ bsum) {
    const int t = threadIdx.x;
    __shared__ int sc[128];
    const int v = (t < NBLK) ? bsum[t] : 0;
    sc[t] = v;
    __syncthreads();
    for (int off = 1; off < 128; off <<= 1) {
        int x = 0;
        if (t >= off) x = sc[t - off];
        __syncthreads();
        sc[t] += x;
        __syncthreads();
    }
    if (t < NBLK) bsum[t] = sc[t] - v;   // exclusive
}

// final: rowptr = exclusive scan of deg; also zero cnt (aliases deg)
__global__ void k_scanfinal(const int* __restrict__ deg, const int* __restrict__ boff,
                            int* __restrict__ rowptr, int* __restrict__ cnt) {
    const int b = blockIdx.x, t = threadIdx.x;
    const int i0 = b * SCAN_CHUNK + t * 4;
    int v[4]; int ts = 0;
#pragma unroll
    for (int k = 0; k < 4; ++k) { const int i = i0 + k; v[k] = (i < NN) ? deg[i] : 0; ts += v[k]; }
    __shared__ int sc[256];
    sc[t] = ts;
    __syncthreads();
    for (int off = 1; off < 256; off <<= 1) {
        int x = 0;
        if (t >= off) x = sc[t - off];
        __syncthreads();
        sc[t] += x;
        __syncthreads();
    }
    int base = boff[b] + (sc[t] - ts);
#pragma unroll
    for (int k = 0; k < 4; ++k) {
        const int i = i0 + k;
        if (i < NN) { rowptr[i] = base; cnt[i] = 0; }
        base += v[k];
    }
    if (b == 0 && t == 0) rowptr[NN] = EE;
}

__global__ void k_scatter(const int* __restrict__ src, const int* __restrict__ dst,
                          const int* __restrict__ rowptr, int* __restrict__ cnt,
                          int* __restrict__ esrc) {
    const int e = blockIdx.x * blockDim.x + threadIdx.x;
    if (e >= EE) return;
    const int d = dst[e];
    const int p = rowptr[d] + atomicAdd(&cnt[d], 1);
    esrc[p] = src[e];
}

// ---------------- fused per-dst GAT layer (no atomics) ----------------
// one wave per dst node: max pass, then fused (den + weighted-z) pass,
// residual + bias folded into the single coalesced write.
__global__ void k_gat_dst(const int* __restrict__ rowptr, const int* __restrict__ esrc,
                          const float* __restrict__ el, const float* __restrict__ er,
                          const float* __restrict__ z, const float* __restrict__ hin,
                          const float* __restrict__ bg, float* __restrict__ hout) {
    const int j  = threadIdx.x & 63;
    const int wv = threadIdx.x >> 6;
    const int hh = j >> 4;
    const int d = blockIdx.x * 4 + wv;
    if (d >= NN) return;
    const int r0 = rowptr[d], r1 = rowptr[d + 1];
    const float erh = er[d * NH + hh];
    float m = -3.4e38f;
    for (int i = r0; i < r1; ++i) {
        const int s = esrc[i];
        m = fmaxf(m, lrelu(el[s * NH + hh] + erh));
    }
    float den = 0.f, sum = 0.f;
    for (int i = r0; i < r1; ++i) {
        const int s = esrc[i];
        const float e = lrelu(el[s * NH + hh] + erh);
        const float w = __expf(e - m);
        den += w;
        sum += w * z[(size_t)s * HID + j];
    }
    float o = hin[(size_t)d * HID + j] + bg[j];
    if (r1 > r0) o += sum / den;
    hout[(size_t)d * HID + j] = o;
}

// LayerNorm + out = hn @ W_out + b_out, one wave per node
__global__ void k_ln_out(const float* __restrict__ h, const float* __restrict__ g,
                         const float* __restrict__ be, const float* __restrict__ Wo,
                         const float* __restrict__ bo, float* __restrict__ out) {
    __shared__ float Ws[HID * OUT_DIM];  // 16 KB
    for (int i = threadIdx.x; i < HID * OUT_DIM; i += blockDim.x) Ws[i] = Wo[i];
    __syncthreads();
    const int j  = threadIdx.x & 63;
    const int vi = threadIdx.x >> 6;
    const float gj = g[j], bej = be[j], boj = bo[j];
    for (int v0 = blockIdx.x * 4; v0 < NN; v0 += gridDim.x * 4) {
        const int v = v0 + vi;
        if (v >= NN) continue;
        const float x = h[(size_t)v * HID + j];
        float s = x;
#pragma unroll
        for (int m = 32; m >= 1; m >>= 1) s += __shfl_xor(s, m, 64);
        const float mu = s * (1.f / 64.f);
        const float dx = x - mu;
        float vs = dx * dx;
#pragma unroll
        for (int m = 32; m >= 1; m >>= 1) vs += __shfl_xor(vs, m, 64);
        const float hn = dx * rsqrtf(vs * (1.f / 64.f) + LN_EPS) * gj + bej;
        float acc = boj;
#pragma unroll
        for (int k = 0; k < HID; ++k) {
            const float hk = __shfl(hn, k, 64);
            acc += hk * Ws[k * OUT_DIM + j];
        }
        out[(size_t)v * OUT_DIM + j] = acc;
    }
}

extern "C" void kernel_launch(void* const* d_in, const int* in_sizes, int n_in,
                              void* d_out, int out_size, void* d_ws, size_t ws_size,
                              hipStream_t stream) {
    const float* X     = (const float*)d_in[0];
    const int*   src   = (const int*)d_in[1];
    const int*   dst   = (const int*)d_in[2];
    const float* W_in  = (const float*)d_in[3];
    const float* b_in  = (const float*)d_in[4];
    // d_in[5..8]: rewiring MLP params — output is dead, skipped entirely
    const float* W_gat = (const float*)d_in[9];   // (L,64,64)
    const float* a_l   = (const float*)d_in[10];  // (L,4,16)
    const float* a_r   = (const float*)d_in[11];
    const float* b_gat = (const float*)d_in[12];  // (L,64)
    const float* ln_g  = (const float*)d_in[13];
    const float* ln_b  = (const float*)d_in[14];
    const float* W_out = (const float*)d_in[15];
    const float* b_out = (const float*)d_in[16];
    float* out = (float*)d_out;

    float* ws = (float*)d_ws;
    float* hA = ws;                       // N*64
    float* hB = hA + (size_t)NN * HID;    // N*64
    float* z  = hB + (size_t)NN * HID;    // N*64
    float* el = z  + (size_t)NN * HID;    // N*4
    float* er = el + (size_t)NN * NH;     // N*4
    int* deg    = (int*)(er + (size_t)NN * NH);  // N ints (reused as cnt)
    int* rowptr = deg + NN;                      // N+1 ints
    int* esrc   = rowptr + NN + 1;               // E ints
    int* bsum   = esrc + EE;                     // NBLK ints

    const int eg = (EE + 255) / 256;

    k_in_gemm<<<1024, 256, 0, stream>>>(X, W_in, b_in, hA);

    // CSR by dst (built once, reused for all 3 layers)
    k_zero_deg<<<(NN + 255) / 256, 256, 0, stream>>>(deg);
    k_hist<<<eg, 256, 0, stream>>>(dst, deg);
    k_blocksum<<<NBLK, 256, 0, stream>>>(deg, bsum);
    k_scanb<<<1, 128, 0, stream>>>(bsum);
    k_scanfinal<<<NBLK, 256, 0, stream>>>(deg, bsum, rowptr, deg);
    k_scatter<<<eg, 256, 0, stream>>>(src, dst, rowptr, deg, esrc);

    float* hin = hA;
    float* hout = hB;
    for (int l = 0; l < NL; ++l) {
        k_zgemm<<<1024, 256, 0, stream>>>(hin, W_gat + (size_t)l * HID * HID,
                                          a_l + (size_t)l * HID, a_r + (size_t)l * HID,
                                          z, el, er);
        k_gat_dst<<<(NN + 3) / 4, 256, 0, stream>>>(rowptr, esrc, el, er, z, hin,
                                                    b_gat + (size_t)l * HID, hout);
        float* t = hin; hin = hout; hout = t;
    }

    k_ln_out<<<1024, 256, 0, stream>>>(hin, ln_g, ln_b, W_out, b_out, out);
}

// Round 3
// 756.627 us; speedup vs baseline: 23.9238x; 1.7403x over previous
//
#include <hip/hip_runtime.h>

#define NN 100000
#define EE 1600000
#define IN_DIM 128
#define HID 64
#define NH 4
#define DH 16
#define NL 3
#define OUT_DIM 64
#define SLOPE 0.2f
#define LN_EPS 1e-5f

#define SCAN_CHUNK 1024
#define NBLK ((NN + SCAN_CHUNK - 1) / SCAN_CHUNK)   // 98

__device__ __forceinline__ float lrelu(float x) {
    return x > 0.f ? x : SLOPE * x;
}
__device__ __forceinline__ float bcast(float x, int lane) {
    return __int_as_float(__builtin_amdgcn_readlane(__float_as_int(x), lane));
}

// h0 = X @ W_in + b_in   (N x 128) @ (128 x 64)
// W transposed+swizzled in LDS, read as ds_read_b128.
__global__ void k_in_gemm(const float* __restrict__ X, const float* __restrict__ W,
                          const float* __restrict__ b, float* __restrict__ h) {
    __shared__ float4 WsT4[IN_DIM * HID / 4];   // 32 KB, [j][p] 16B chunks
    float* WsT = (float*)WsT4;
    for (int idx = threadIdx.x; idx < IN_DIM * HID; idx += blockDim.x) {
        const int j = idx >> 7, k = idx & 127;          // j: out col, k: in row
        const int p = (k >> 2) ^ (threadIdx.x & 0, 0) ; // placeholder avoided below
        (void)p;
        const int pp = (k >> 2) ^ (j & 15);
        WsT[j * IN_DIM + pp * 4 + (k & 3)] = W[k * HID + j];
    }
    __syncthreads();
    const int j  = threadIdx.x & 63;
    const int vi = threadIdx.x >> 6;
    const float bj = b[j];
    const float* wrow = WsT + j * IN_DIM;
    const int sw = j & 15;
    for (int v0 = blockIdx.x * 4; v0 < NN; v0 += gridDim.x * 4) {
        const int v = v0 + vi;
        if (v >= NN) continue;
        const float4* xr = (const float4*)(X + (size_t)v * IN_DIM);
        float acc = bj;
#pragma unroll
        for (int c = 0; c < 32; ++c) {
            const float4 xv = xr[c];
            const float4 wv = *(const float4*)(wrow + (((c ^ sw) ) << 2));
            acc += xv.x * wv.x + xv.y * wv.y + xv.z * wv.z + xv.w * wv.w;
        }
        h[(size_t)v * HID + j] = acc;
    }
}

// z = h @ W (64x64), plus el[v,h] = sum_d z*al, er[v,h] = sum_d z*ar
__global__ void k_zgemm(const float* __restrict__ h, const float* __restrict__ W,
                        const float* __restrict__ al, const float* __restrict__ ar,
                        float* __restrict__ z, float* __restrict__ el, float* __restrict__ er) {
    __shared__ float4 WsT4[HID * HID / 4];      // 16 KB
    float* WsT = (float*)WsT4;
    for (int idx = threadIdx.x; idx < HID * HID; idx += blockDim.x) {
        const int j = idx >> 6, k = idx & 63;
        const int p = (k >> 2) ^ (j & 15);
        WsT[j * HID + p * 4 + (k & 3)] = W[k * HID + j];
    }
    __syncthreads();
    const int j  = threadIdx.x & 63;
    const int vi = threadIdx.x >> 6;
    const int head = j >> 4;
    const float alj = al[j];
    const float arj = ar[j];
    const float* wrow = WsT + j * HID;
    const int sw = j & 15;
    for (int v0 = blockIdx.x * 4; v0 < NN; v0 += gridDim.x * 4) {
        const int v = v0 + vi;
        if (v >= NN) continue;
        const float4* hr = (const float4*)(h + (size_t)v * HID);
        float acc = 0.f;
#pragma unroll
        for (int c = 0; c < 16; ++c) {
            const float4 hv = hr[c];
            const float4 wv = *(const float4*)(wrow + ((c ^ sw) << 2));
            acc += hv.x * wv.x + hv.y * wv.y + hv.z * wv.z + hv.w * wv.w;
        }
        z[(size_t)v * HID + j] = acc;
        float pl = acc * alj, pr = acc * arj;
#pragma unroll
        for (int m = 8; m >= 1; m >>= 1) {
            pl += __shfl_xor(pl, m, 64);
            pr += __shfl_xor(pr, m, 64);
        }
        if ((j & 15) == 0) {
            el[v * NH + head] = pl;
            er[v * NH + head] = pr;
        }
    }
}

// ---------------- CSR build (once per launch) ----------------

__global__ void k_zero_deg(int* __restrict__ deg) {
    const int i = blockIdx.x * blockDim.x + threadIdx.x;
    if (i < NN) deg[i] = 0;
}

__global__ void k_hist(const int* __restrict__ dst, int* __restrict__ deg) {
    const int e = blockIdx.x * blockDim.x + threadIdx.x;
    if (e < EE) atomicAdd(&deg[dst[e]], 1);
}

__global__ void k_blocksum(const int* __restrict__ deg, int* __restrict__ bsum) {
    const int b = blockIdx.x, t = threadIdx.x;
    const int i0 = b * SCAN_CHUNK + t * 4;
    int s = 0;
#pragma unroll
    for (int k = 0; k < 4; ++k) { const int i = i0 + k; if (i < NN) s += deg[i]; }
#pragma unroll
    for (int m = 32; m >= 1; m >>= 1) s += __shfl_xor(s, m, 64);
    __shared__ int wsum[4];
    if ((t & 63) == 0) wsum[t >> 6] = s;
    __syncthreads();
    if (t == 0) bsum[b] = wsum[0] + wsum[1] + wsum[2] + wsum[3];
}

__global__ void k_scanb(int* __restrict__ bsum) {
    const int t = threadIdx.x;
    __shared__ int sc[128];
    const int v = (t < NBLK) ? bsum[t] : 0;
    sc[t] = v;
    __syncthreads();
    for (int off = 1; off < 128; off <<= 1) {
        int x = 0;
        if (t >= off) x = sc[t - off];
        __syncthreads();
        sc[t] += x;
        __syncthreads();
    }
    if (t < NBLK) bsum[t] = sc[t] - v;   // exclusive
}

__global__ void k_scanfinal(const int* __restrict__ deg, const int* __restrict__ boff,
                            int* __restrict__ rowptr, int* __restrict__ cnt) {
    const int b = blockIdx.x, t = threadIdx.x;
    const int i0 = b * SCAN_CHUNK + t * 4;
    int v[4]; int ts = 0;
#pragma unroll
    for (int k = 0; k < 4; ++k) { const int i = i0 + k; v[k] = (i < NN) ? deg[i] : 0; ts += v[k]; }
    __shared__ int sc[256];
    sc[t] = ts;
    __syncthreads();
    for (int off = 1; off < 256; off <<= 1) {
        int x = 0;
        if (t >= off) x = sc[t - off];
        __syncthreads();
        sc[t] += x;
        __syncthreads();
    }
    int base = boff[b] + (sc[t] - ts);
#pragma unroll
    for (int k = 0; k < 4; ++k) {
        const int i = i0 + k;
        if (i < NN) { rowptr[i] = base; cnt[i] = 0; }
        base += v[k];
    }
    if (b == 0 && t == 0) rowptr[NN] = EE;
}

__global__ void k_scatter(const int* __restrict__ src, const int* __restrict__ dst,
                          const int* __restrict__ rowptr, int* __restrict__ cnt,
                          int* __restrict__ esrc) {
    const int e = blockIdx.x * blockDim.x + threadIdx.x;
    if (e >= EE) return;
    const int d = dst[e];
    const int p = rowptr[d] + atomicAdd(&cnt[d], 1);
    esrc[p] = src[e];
}

// ---------------- fused per-dst GAT layer (single pass, no max, no atomics) ----------------
__global__ void k_gat_dst(const int* __restrict__ rowptr, const int* __restrict__ esrc,
                          const float* __restrict__ el, const float* __restrict__ er,
                          const float* __restrict__ z, const float* __restrict__ hin,
                          const float* __restrict__ bg, float* __restrict__ hout) {
    const int j  = threadIdx.x & 63;
    const int wv = threadIdx.x >> 6;
    const int hh = j >> 4;
    const int d = blockIdx.x * 4 + wv;
    if (d >= NN) return;
    const int r0 = rowptr[d], r1 = rowptr[d + 1];
    const float erh = er[d * NH + hh];
    float den = 0.f, sum = 0.f;
    int i = r0;
    for (; i + 4 <= r1; i += 4) {
        const int s0 = esrc[i], s1 = esrc[i + 1], s2 = esrc[i + 2], s3 = esrc[i + 3];
        const float a0 = el[s0 * NH + hh];
        const float a1 = el[s1 * NH + hh];
        const float a2 = el[s2 * NH + hh];
        const float a3 = el[s3 * NH + hh];
        const float z0 = z[(size_t)s0 * HID + j];
        const float z1 = z[(size_t)s1 * HID + j];
        const float z2 = z[(size_t)s2 * HID + j];
        const float z3 = z[(size_t)s3 * HID + j];
        const float w0 = __expf(lrelu(a0 + erh));
        const float w1 = __expf(lrelu(a1 + erh));
        const float w2 = __expf(lrelu(a2 + erh));
        const float w3 = __expf(lrelu(a3 + erh));
        den += (w0 + w1) + (w2 + w3);
        sum += (w0 * z0 + w1 * z1) + (w2 * z2 + w3 * z3);
    }
    for (; i < r1; ++i) {
        const int s = esrc[i];
        const float w = __expf(lrelu(el[s * NH + hh] + erh));
        den += w;
        sum += w * z[(size_t)s * HID + j];
    }
    float o = hin[(size_t)d * HID + j] + bg[j];
    if (r1 > r0) o += sum / den;
    hout[(size_t)d * HID + j] = o;
}

// LayerNorm + out = hn @ W_out + b_out, one wave per node
__global__ void k_ln_out(const float* __restrict__ h, const float* __restrict__ g,
                         const float* __restrict__ be, const float* __restrict__ Wo,
                         const float* __restrict__ bo, float* __restrict__ out) {
    __shared__ float4 WsT4[HID * OUT_DIM / 4];  // 16 KB transposed+swizzled
    float* WsT = (float*)WsT4;
    for (int idx = threadIdx.x; idx < HID * OUT_DIM; idx += blockDim.x) {
        const int j = idx >> 6, k = idx & 63;
        const int p = (k >> 2) ^ (j & 15);
        WsT[j * HID + p * 4 + (k & 3)] = Wo[k * OUT_DIM + j];
    }
    __syncthreads();
    const int j  = threadIdx.x & 63;
    const int vi = threadIdx.x >> 6;
    const float gj = g[j], bej = be[j], boj = bo[j];
    const float* wrow = WsT + j * HID;
    const int sw = j & 15;
    for (int v0 = blockIdx.x * 4; v0 < NN; v0 += gridDim.x * 4) {
        const int v = v0 + vi;
        if (v >= NN) continue;
        const float x = h[(size_t)v * HID + j];
        float s = x;
#pragma unroll
        for (int m = 32; m >= 1; m >>= 1) s += __shfl_xor(s, m, 64);
        const float mu = s * (1.f / 64.f);
        const float dx = x - mu;
        float vs = dx * dx;
#pragma unroll
        for (int m = 32; m >= 1; m >>= 1) vs += __shfl_xor(vs, m, 64);
        const float hn = dx * rsqrtf(vs * (1.f / 64.f) + LN_EPS) * gj + bej;
        float acc = boj;
#pragma unroll
        for (int c = 0; c < 16; ++c) {
            const float4 wv = *(const float4*)(wrow + ((c ^ sw) << 2));
            acc += bcast(hn, 4 * c + 0) * wv.x;
            acc += bcast(hn, 4 * c + 1) * wv.y;
            acc += bcast(hn, 4 * c + 2) * wv.z;
            acc += bcast(hn, 4 * c + 3) * wv.w;
        }
        out[(size_t)v * OUT_DIM + j] = acc;
    }
}

extern "C" void kernel_launch(void* const* d_in, const int* in_sizes, int n_in,
                              void* d_out, int out_size, void* d_ws, size_t ws_size,
                              hipStream_t stream) {
    const float* X     = (const float*)d_in[0];
    const int*   src   = (const int*)d_in[1];
    const int*   dst   = (const int*)d_in[2];
    const float* W_in  = (const float*)d_in[3];
    const float* b_in  = (const float*)d_in[4];
    // d_in[5..8]: rewiring MLP params — output is dead, skipped entirely
    const float* W_gat = (const float*)d_in[9];   // (L,64,64)
    const float* a_l   = (const float*)d_in[10];  // (L,4,16)
    const float* a_r   = (const float*)d_in[11];
    const float* b_gat = (const float*)d_in[12];  // (L,64)
    const float* ln_g  = (const float*)d_in[13];
    const float* ln_b  = (const float*)d_in[14];
    const float* W_out = (const float*)d_in[15];
    const float* b_out = (const float*)d_in[16];
    float* out = (float*)d_out;

    float* ws = (float*)d_ws;
    float* hA = ws;                       // N*64
    float* hB = hA + (size_t)NN * HID;    // N*64
    float* z  = hB + (size_t)NN * HID;    // N*64
    float* el = z  + (size_t)NN * HID;    // N*4
    float* er = el + (size_t)NN * NH;     // N*4
    int* deg    = (int*)(er + (size_t)NN * NH);  // N ints (reused as cnt)
    int* rowptr = deg + NN;                      // N+1 ints
    int* esrc   = rowptr + NN + 1;               // E ints
    int* bsum   = esrc + EE;                     // NBLK ints

    const int eg = (EE + 255) / 256;

    k_in_gemm<<<1024, 256, 0, stream>>>(X, W_in, b_in, hA);

    // CSR by dst (built once, reused for all 3 layers)
    k_zero_deg<<<(NN + 255) / 256, 256, 0, stream>>>(deg);
    k_hist<<<eg, 256, 0, stream>>>(dst, deg);
    k_blocksum<<<NBLK, 256, 0, stream>>>(deg, bsum);
    k_scanb<<<1, 128, 0, stream>>>(bsum);
    k_scanfinal<<<NBLK, 256, 0, stream>>>(deg, bsum, rowptr, deg);
    k_scatter<<<eg, 256, 0, stream>>>(src, dst, rowptr, deg, esrc);

    float* hin = hA;
    float* hout = hB;
    for (int l = 0; l < NL; ++l) {
        k_zgemm<<<1024, 256, 0, stream>>>(hin, W_gat + (size_t)l * HID * HID,
                                          a_l + (size_t)l * HID, a_r + (size_t)l * HID,
                                          z, el, er);
        k_gat_dst<<<(NN + 3) / 4, 256, 0, stream>>>(rowptr, esrc, el, er, z, hin,
                                                    b_gat + (size_t)l * HID, hout);
        float* t = hin; hin = hout; hout = t;
    }

    k_ln_out<<<1024, 256, 0, stream>>>(hin, ln_g, ln_b, W_out, b_out, out);
}